// Round 17
// baseline (636.378 us; speedup 1.0000x reference)
//
#include <hip/hip_runtime.h>
#include <hip/hip_bf16.h>
#include <math.h>

#define D_MODEL 256
#define D_INNER 512
#define D_STATE 16
#define D_CONV 4
#define DT_RANK 16
#define N_LAYERS 4
#define CITY 300
#define BATCH 32
#define SEQ 300
#define NTOK (BATCH * SEQ)   // 9600
#define NSEG 15
#define SEGLEN (SEQ / NSEG)  // 20

typedef __attribute__((ext_vector_type(8))) short short8v;
typedef __attribute__((ext_vector_type(4))) float f32x4;

__device__ __forceinline__ float fast_sig(float x) {
    return __builtin_amdgcn_rcpf(1.f + __expf(-x));
}

__device__ __forceinline__ unsigned short f2b(float a) {
    __hip_bfloat16 h = __float2bfloat16(a);
    return *reinterpret_cast<unsigned short*>(&h);
}

__device__ __forceinline__ float b2f(unsigned short u) {
    unsigned int x = ((unsigned int)u) << 16;
    return __uint_as_float(x);
}

// ---------------- all weight conversions, vectorized ----------------
__global__ void cvt4_kernel(const float* __restrict__ s0, unsigned short* __restrict__ d0, int n0,
                            const float* __restrict__ s1, unsigned short* __restrict__ d1, int n1,
                            const float* __restrict__ s2, unsigned short* __restrict__ d2, int n2,
                            const float* __restrict__ s3, unsigned short* __restrict__ d3, int n3) {
    int stride = gridDim.x * blockDim.x;
    int tid = blockIdx.x * blockDim.x + threadIdx.x;
    for (int i = tid; i < n0 / 4; i += stride) {
        float4 v = ((const float4*)s0)[i];
        ushort4 o; o.x = f2b(v.x); o.y = f2b(v.y); o.z = f2b(v.z); o.w = f2b(v.w);
        ((ushort4*)d0)[i] = o;
    }
    for (int i = tid; i < n1 / 4; i += stride) {
        float4 v = ((const float4*)s1)[i];
        ushort4 o; o.x = f2b(v.x); o.y = f2b(v.y); o.z = f2b(v.z); o.w = f2b(v.w);
        ((ushort4*)d1)[i] = o;
    }
    for (int i = tid; i < n2 / 4; i += stride) {
        float4 v = ((const float4*)s2)[i];
        ushort4 o; o.x = f2b(v.x); o.y = f2b(v.y); o.z = f2b(v.z); o.w = f2b(v.w);
        ((ushort4*)d2)[i] = o;
    }
    for (int i = tid; i < n3 / 4; i += stride) {
        float4 v = ((const float4*)s3)[i];
        ushort4 o; o.x = f2b(v.x); o.y = f2b(v.y); o.z = f2b(v.z); o.w = f2b(v.w);
        ((ushort4*)d3)[i] = o;
    }
}

// ---------------- embedding + layer-0 residual init + LN (fused) ----------------
__global__ void embed_ln_kernel(const float* __restrict__ coords,
                                const float* __restrict__ eW,
                                const float* __restrict__ eb,
                                const float* __restrict__ w,
                                const float* __restrict__ b,
                                float* __restrict__ resid,
                                unsigned short* __restrict__ hb) {
    int t = blockIdx.x, d = threadIdx.x;
    float c0 = coords[t * 2 + 0];
    float c1 = coords[t * 2 + 1];
    float r = c0 * eW[d * 2 + 0] + c1 * eW[d * 2 + 1] + eb[d];
    resid[t * D_MODEL + d] = r;
    float s1 = r, s2 = r * r;
#pragma unroll
    for (int m = 1; m < 64; m <<= 1) {
        s1 += __shfl_xor(s1, m);
        s2 += __shfl_xor(s2, m);
    }
    __shared__ float p1[4], p2[4];
    if ((d & 63) == 0) { p1[d >> 6] = s1; p2[d >> 6] = s2; }
    __syncthreads();
    s1 = (p1[0] + p1[1]) + (p1[2] + p1[3]);
    s2 = (p2[0] + p2[1]) + (p2[2] + p2[3]);
    float mean = s1 * (1.f / D_MODEL);
    float var = s2 * (1.f / D_MODEL) - mean * mean;
    hb[t * D_MODEL + d] = f2b((r - mean) * rsqrtf(var + 1e-5f) * w[d] + b[d]);
}

// ------------- bf16-in MFMA GEMM: C[t,n] = sum_k A[t,k] * W[n,k] -------------
template <int BM, int BN, bool GN, bool OB>
__global__ __launch_bounds__(256, 2) void gemm_mfma(const unsigned short* __restrict__ A,
                                                    const unsigned short* __restrict__ W,
                                                    void* __restrict__ C, int N, int K) {
    constexpr int TI = BM / 32;
    constexpr int TJ = BN / 32;
    __shared__ short Als[BM * 32];
    __shared__ short Bls[BN * 32];
    const int tid = threadIdx.x;
    const int lane = tid & 63, wid = tid >> 6;
    const int wr = wid >> 1, wc = wid & 1;
    const int t0 = blockIdx.x * BM, n0 = blockIdx.y * BN;
    f32x4 acc[TI][TJ] = {};

    for (int k0 = 0; k0 < K; k0 += 32) {
#pragma unroll
        for (int it = 0; it < BM / 64; ++it) {
            int s = tid + it * 256;
            int m = s >> 2, q = s & 3;
            uint4 p = *(const uint4*)(A + (size_t)(t0 + m) * K + k0 + q * 8);
            *(uint4*)&Als[(((m >> 4) * 4 + q) * 16 + (m & 15)) * 8] = p;
        }
#pragma unroll
        for (int it = 0; it < BN / 64; ++it) {
            int s = tid + it * 256;
            int n = s >> 2, q = s & 3;
            int nrow = n0 + n;
            uint4 p = make_uint4(0u, 0u, 0u, 0u);
            if (!GN || nrow < N)
                p = *(const uint4*)(W + (size_t)nrow * K + k0 + q * 8);
            *(uint4*)&Bls[(((n >> 4) * 4 + q) * 16 + (n & 15)) * 8] = p;
        }
        __syncthreads();
        short8v af[TI], bf[TJ];
#pragma unroll
        for (int i = 0; i < TI; i++)
            af[i] = *(const short8v*)&Als[(wr * TI + i) * 512 + lane * 8];
#pragma unroll
        for (int j = 0; j < TJ; j++)
            bf[j] = *(const short8v*)&Bls[(wc * TJ + j) * 512 + lane * 8];
#pragma unroll
        for (int i = 0; i < TI; i++)
#pragma unroll
            for (int j = 0; j < TJ; j++)
                acc[i][j] = __builtin_amdgcn_mfma_f32_16x16x32_bf16(
                    af[i], bf[j], acc[i][j], 0, 0, 0);
        __syncthreads();
    }
    const int rq = lane >> 4, cn = lane & 15;
#pragma unroll
    for (int i = 0; i < TI; i++) {
        int trow = t0 + wr * (BM / 2) + i * 16 + rq * 4;
#pragma unroll
        for (int j = 0; j < TJ; j++) {
            int ncol = n0 + wc * (BN / 2) + j * 16 + cn;
            if (!GN || ncol < N) {
#pragma unroll
                for (int reg = 0; reg < 4; reg++) {
                    if constexpr (OB)
                        ((unsigned short*)C)[(size_t)(trow + reg) * N + ncol] =
                            f2b(acc[i][j][reg]);
                    else
                        ((float*)C)[(size_t)(trow + reg) * N + ncol] = acc[i][j][reg];
                }
            }
        }
    }
}

// ------------- fused conv+silu (-> xcb) + xproj GEMM (-> dbl) -------------
// BM=64 tokens, BN=48, K=512; 4 waves stacked on M (16 rows each), TJ=3.
// A-tile staged by computing causal conv + SiLU on the fly; result also
// written to xcb (each (t,ch) covered exactly once across grid x K-chunks).
__global__ __launch_bounds__(256, 2) void conv_xproj_gemm(
    const unsigned short* __restrict__ xzb, const float* __restrict__ cW,
    const float* __restrict__ cb, const unsigned short* __restrict__ W,
    unsigned short* __restrict__ xcb, float* __restrict__ dbl) {
    __shared__ short Als[64 * 32];
    __shared__ short Bls[48 * 32];
    const int tid = threadIdx.x;
    const int lane = tid & 63, wid = tid >> 6;
    const int t0 = blockIdx.x * 64;
    f32x4 acc[3] = {};

    for (int k0 = 0; k0 < D_INNER; k0 += 32) {
        // stage A (64 rows x 32 ch): 256 quad-slots, 1/thread, conv fused
        {
            int m = tid >> 2, q = tid & 3;
            int t = t0 + m;
            int l = t % SEQ;
            int c0 = k0 + q * 8;
            float4 cwv[8];
#pragma unroll
            for (int c = 0; c < 8; c++) cwv[c] = *(const float4*)(cW + (c0 + c) * 4);
            float a[8];
#pragma unroll
            for (int c = 0; c < 8; c++) a[c] = cb[c0 + c];
#pragma unroll
            for (int k = 0; k < D_CONV; k++) {
                if (l - 3 + k >= 0) {
                    const unsigned short* src = xzb + (size_t)(t - 3 + k) * 1024 + c0;
                    ushort4 u0 = *(const ushort4*)src;
                    ushort4 u1 = *(const ushort4*)(src + 4);
                    unsigned short uu[8] = {u0.x, u0.y, u0.z, u0.w, u1.x, u1.y, u1.z, u1.w};
#pragma unroll
                    for (int c = 0; c < 8; c++) {
                        float wk = (k == 0) ? cwv[c].x : (k == 1) ? cwv[c].y
                                  : (k == 2) ? cwv[c].z : cwv[c].w;
                        a[c] = fmaf(b2f(uu[c]), wk, a[c]);
                    }
                }
            }
            unsigned short ob[8];
#pragma unroll
            for (int c = 0; c < 8; c++) {
                float v = a[c] * fast_sig(a[c]);
                ob[c] = f2b(v);
            }
            uint4 p = *(uint4*)ob;
            *(uint4*)(xcb + (size_t)t * 512 + c0) = p;
            *(uint4*)&Als[(((m >> 4) * 4 + q) * 16 + (m & 15)) * 8] = p;
        }
        // stage B (48 rows x 32): 192 quad-slots
        if (tid < 192) {
            int n = tid >> 2, q = tid & 3;
            uint4 p = *(const uint4*)(W + (size_t)n * D_INNER + k0 + q * 8);
            *(uint4*)&Bls[(((n >> 4) * 4 + q) * 16 + (n & 15)) * 8] = p;
        }
        __syncthreads();
        short8v af = *(const short8v*)&Als[wid * 512 + lane * 8];
        short8v bf[3];
#pragma unroll
        for (int j = 0; j < 3; j++)
            bf[j] = *(const short8v*)&Bls[j * 512 + lane * 8];
#pragma unroll
        for (int j = 0; j < 3; j++)
            acc[j] = __builtin_amdgcn_mfma_f32_16x16x32_bf16(af, bf[j], acc[j], 0, 0, 0);
        __syncthreads();
    }
    const int rq = lane >> 4, cn = lane & 15;
    int trow = t0 + wid * 16 + rq * 4;
#pragma unroll
    for (int j = 0; j < 3; j++) {
        int ncol = j * 16 + cn;
#pragma unroll
        for (int reg = 0; reg < 4; reg++)
            dbl[(size_t)(trow + reg) * 48 + ncol] = acc[j][reg];
    }
}

// ------------- out_proj GEMM + residual add + LN/RMS fused epilogue -------------
template <bool RMS>
__global__ __launch_bounds__(256, 2) void gemm_out_ln(const unsigned short* __restrict__ A,
                                                      const unsigned short* __restrict__ W,
                                                      float* __restrict__ resid,
                                                      const float* __restrict__ w,
                                                      const float* __restrict__ b,
                                                      unsigned short* __restrict__ hb) {
    constexpr int TI = 2, TJ = 8;
    const int K = D_INNER;
    __shared__ short Als[64 * 32];
    __shared__ short Bls[256 * 32];
    __shared__ float rs1[2][64], rs2[2][64];
    const int tid = threadIdx.x;
    const int lane = tid & 63, wid = tid >> 6;
    const int wr = wid >> 1, wc = wid & 1;
    const int t0 = blockIdx.x * 64;
    f32x4 acc[TI][TJ] = {};

    for (int k0 = 0; k0 < K; k0 += 32) {
        {
            int s = tid;
            int m = s >> 2, q = s & 3;
            uint4 p = *(const uint4*)(A + (size_t)(t0 + m) * K + k0 + q * 8);
            *(uint4*)&Als[(((m >> 4) * 4 + q) * 16 + (m & 15)) * 8] = p;
        }
#pragma unroll
        for (int it = 0; it < 4; ++it) {
            int s = tid + it * 256;
            int n = s >> 2, q = s & 3;
            uint4 p = *(const uint4*)(W + (size_t)n * K + k0 + q * 8);
            *(uint4*)&Bls[(((n >> 4) * 4 + q) * 16 + (n & 15)) * 8] = p;
        }
        __syncthreads();
        short8v af[TI], bf[TJ];
#pragma unroll
        for (int i = 0; i < TI; i++)
            af[i] = *(const short8v*)&Als[(wr * TI + i) * 512 + lane * 8];
#pragma unroll
        for (int j = 0; j < TJ; j++)
            bf[j] = *(const short8v*)&Bls[(wc * TJ + j) * 512 + lane * 8];
#pragma unroll
        for (int i = 0; i < TI; i++)
#pragma unroll
            for (int j = 0; j < TJ; j++)
                acc[i][j] = __builtin_amdgcn_mfma_f32_16x16x32_bf16(
                    af[i], bf[j], acc[i][j], 0, 0, 0);
        __syncthreads();
    }
    const int rq = lane >> 4, cn = lane & 15;
    float s1p[TI][4], s2p[TI][4];
#pragma unroll
    for (int i = 0; i < TI; i++) {
        int trow = t0 + wr * 32 + i * 16 + rq * 4;
#pragma unroll
        for (int reg = 0; reg < 4; reg++) { s1p[i][reg] = 0.f; s2p[i][reg] = 0.f; }
#pragma unroll
        for (int j = 0; j < TJ; j++) {
            int c = wc * 128 + j * 16 + cn;
#pragma unroll
            for (int reg = 0; reg < 4; reg++) {
                float rv = acc[i][j][reg] + resid[(size_t)(trow + reg) * D_MODEL + c];
                acc[i][j][reg] = rv;
                s1p[i][reg] += rv;
                s2p[i][reg] = fmaf(rv, rv, s2p[i][reg]);
            }
        }
    }
#pragma unroll
    for (int m = 1; m < 16; m <<= 1) {
#pragma unroll
        for (int i = 0; i < TI; i++)
#pragma unroll
            for (int reg = 0; reg < 4; reg++) {
                s1p[i][reg] += __shfl_xor(s1p[i][reg], m);
                s2p[i][reg] += __shfl_xor(s2p[i][reg], m);
            }
    }
    if (cn == 0) {
#pragma unroll
        for (int i = 0; i < TI; i++)
#pragma unroll
            for (int reg = 0; reg < 4; reg++) {
                int rloc = wr * 32 + i * 16 + rq * 4 + reg;
                rs1[wc][rloc] = s1p[i][reg];
                rs2[wc][rloc] = s2p[i][reg];
            }
    }
    __syncthreads();
    float wv[TJ], bv[TJ];
#pragma unroll
    for (int j = 0; j < TJ; j++) {
        int c = wc * 128 + j * 16 + cn;
        wv[j] = w[c];
        bv[j] = b[c];
    }
#pragma unroll
    for (int i = 0; i < TI; i++) {
        int trow = t0 + wr * 32 + i * 16 + rq * 4;
#pragma unroll
        for (int reg = 0; reg < 4; reg++) {
            int rloc = wr * 32 + i * 16 + rq * 4 + reg;
            float S1 = rs1[0][rloc] + rs1[1][rloc];
            float S2 = rs2[0][rloc] + rs2[1][rloc];
            float mean, rstd;
            if constexpr (RMS) {
                mean = 0.f;
                rstd = rsqrtf(S2 * (1.f / D_MODEL) + 1e-5f);
            } else {
                mean = S1 * (1.f / D_MODEL);
                float var = S2 * (1.f / D_MODEL) - mean * mean;
                rstd = rsqrtf(var + 1e-5f);
            }
#pragma unroll
            for (int j = 0; j < TJ; j++) {
                int c = wc * 128 + j * 16 + cn;
                float rv = acc[i][j][reg];
                hb[(size_t)(trow + reg) * D_MODEL + c] =
                    f2b((rv - mean) * rstd * wv[j] + bv[j]);
                if constexpr (!RMS)
                    resid[(size_t)(trow + reg) * D_MODEL + c] = rv;
            }
        }
    }
}

// ========== block-local 3-phase scan; dtt stashed in global scratch ==========
__global__ __launch_bounds__(960) void scan_block(
    const unsigned short* __restrict__ xcb, const float* __restrict__ dbl,
    const unsigned short* __restrict__ xzb,
    const float* __restrict__ A_log, const float* __restrict__ Dskip,
    const float* __restrict__ dtW, const float* __restrict__ dtb,
    float* __restrict__ dts, unsigned short* __restrict__ yb) {
    __shared__ float lh[NSEG * D_STATE * 64];
    __shared__ float lsd[NSEG * 64];
    const int dg = blockIdx.x, b = blockIdx.y;
    const int tid = threadIdx.x;
    const int lane = tid & 63;
    const int seg = __builtin_amdgcn_readfirstlane(tid >> 6);  // wave-uniform
    const int d = (dg << 6) + lane;
    const float LOG2E = 1.44269504088896340736f;
    float ArowL2[D_STATE], dWr[DT_RANK];
#pragma unroll
    for (int s4 = 0; s4 < 4; s4++) {
        float4 v = *(const float4*)(A_log + (size_t)d * D_STATE + s4 * 4);
        ArowL2[s4 * 4 + 0] = -__expf(v.x) * LOG2E;
        ArowL2[s4 * 4 + 1] = -__expf(v.y) * LOG2E;
        ArowL2[s4 * 4 + 2] = -__expf(v.z) * LOG2E;
        ArowL2[s4 * 4 + 3] = -__expf(v.w) * LOG2E;
        float4 w = *(const float4*)(dtW + (size_t)d * DT_RANK + s4 * 4);
        dWr[s4 * 4 + 0] = w.x; dWr[s4 * 4 + 1] = w.y;
        dWr[s4 * 4 + 2] = w.z; dWr[s4 * 4 + 3] = w.w;
    }
    const float dtbv = dtb[d], dsk = Dskip[d];
    const size_t tb = (size_t)b * SEQ + (size_t)seg * SEGLEN;
    const float* __restrict__ dr = dbl + tb * 48;
    const unsigned short* __restrict__ xp = xcb + tb * 512 + d;
    const unsigned short* __restrict__ zp = xzb + tb * 1024 + 512 + d;
    float* __restrict__ dtp = dts + tb * 512 + d;
    unsigned short* __restrict__ yp = yb + tb * 512 + d;

    // ---------------- phase 1 ----------------
    {
        float h[D_STATE];
#pragma unroll
        for (int s = 0; s < D_STATE; s++) h[s] = 0.f;
        float sdt = 0.f;
        float dbA[32], dbB[32];
#pragma unroll
        for (int i = 0; i < 8; i++) ((float4*)dbA)[i] = ((const float4*)dr)[i];
        float xv = b2f(xp[0]);
        for (int l = 0; l < SEGLEN; l += 2) {
            const float4* nr1 = (const float4*)(dr + (size_t)(l + 1) * 48);
#pragma unroll
            for (int i = 0; i < 8; i++) ((float4*)dbB)[i] = nr1[i];
            float xv1 = b2f(xp[(size_t)(l + 1) * 512]);
            {
                float a0 = dtbv, a1 = 0.f, a2 = 0.f, a3 = 0.f;
#pragma unroll
                for (int r = 0; r < 4; r++) {
                    a0 = fmaf(dbA[r], dWr[r], a0);
                    a1 = fmaf(dbA[4 + r], dWr[4 + r], a1);
                    a2 = fmaf(dbA[8 + r], dWr[8 + r], a2);
                    a3 = fmaf(dbA[12 + r], dWr[12 + r], a3);
                }
                float acc = (a0 + a1) + (a2 + a3);
                float dtt = fmaxf(acc, 0.f) + __logf(1.f + __expf(-fabsf(acc)));
                dtp[(size_t)l * 512] = dtt;
                sdt += dtt;
                float dtx = dtt * xv;
#pragma unroll
                for (int s = 0; s < D_STATE; s++) {
                    float dA = exp2f(dtt * ArowL2[s]);
                    h[s] = fmaf(dA, h[s], dtx * dbA[16 + s]);
                }
            }
            const float4* nr2 = (const float4*)(dr + (size_t)(l + 2) * 48);
#pragma unroll
            for (int i = 0; i < 8; i++) ((float4*)dbA)[i] = nr2[i];
            float xv2 = b2f(xp[(size_t)(l + 2) * 512]);
            if (l + 1 < SEGLEN) {
                float a0 = dtbv, a1 = 0.f, a2 = 0.f, a3 = 0.f;
#pragma unroll
                for (int r = 0; r < 4; r++) {
                    a0 = fmaf(dbB[r], dWr[r], a0);
                    a1 = fmaf(dbB[4 + r], dWr[4 + r], a1);
                    a2 = fmaf(dbB[8 + r], dWr[8 + r], a2);
                    a3 = fmaf(dbB[12 + r], dWr[12 + r], a3);
                }
                float acc = (a0 + a1) + (a2 + a3);
                float dtt = fmaxf(acc, 0.f) + __logf(1.f + __expf(-fabsf(acc)));
                dtp[(size_t)(l + 1) * 512] = dtt;
                sdt += dtt;
                float dtx = dtt * xv1;
#pragma unroll
                for (int s = 0; s < D_STATE; s++) {
                    float dA = exp2f(dtt * ArowL2[s]);
                    h[s] = fmaf(dA, h[s], dtx * dbB[16 + s]);
                }
            }
            xv = xv2;
        }
#pragma unroll
        for (int s = 0; s < D_STATE; s++) lh[(seg * D_STATE + s) * 64 + lane] = h[s];
        lsd[seg * 64 + lane] = sdt;
    }
    __syncthreads();
    // ---------------- phase 2 ----------------
    for (int it = tid; it < D_STATE * 64; it += 960) {
        int ch = it & 63, s = it >> 6;
        float As2 = -__expf(A_log[(size_t)((dg << 6) + ch) * D_STATE + s]) * LOG2E;
        float H = 0.f;
        for (int sg = 0; sg < NSEG; sg++) {
            float hl = lh[(sg * D_STATE + s) * 64 + ch];
            float sd = lsd[sg * 64 + ch];
            lh[(sg * D_STATE + s) * 64 + ch] = H;
            H = fmaf(exp2f(As2 * sd), H, hl);
        }
    }
    __syncthreads();
    // ---------------- phase 3 ----------------
    {
        float h[D_STATE];
#pragma unroll
        for (int s = 0; s < D_STATE; s++) h[s] = lh[(seg * D_STATE + s) * 64 + lane];
        float dbA[32], dbB[32];
#pragma unroll
        for (int i = 0; i < 8; i++) ((float4*)dbA)[i] = ((const float4*)(dr + 16))[i];
        float xv = b2f(xp[0]), zv = b2f(zp[0]);
        float dt0 = dtp[0];
        for (int l = 0; l < SEGLEN; l += 2) {
            const float4* nr1 = (const float4*)(dr + (size_t)(l + 1) * 48 + 16);
#pragma unroll
            for (int i = 0; i < 8; i++) ((float4*)dbB)[i] = nr1[i];
            float xv1 = b2f(xp[(size_t)(l + 1) * 512]);
            float zv1 = b2f(zp[(size_t)(l + 1) * 1024]);
            float dt1 = dtp[(size_t)(l + 1) * 512];
            {
                float dtt = dt0;
                float dtx = dtt * xv;
                float y0 = 0.f, y1 = 0.f, y2 = 0.f, y3 = 0.f;
#pragma unroll
                for (int s = 0; s < 4; s++) {
                    float dA0 = exp2f(dtt * ArowL2[s]);
                    float dA1 = exp2f(dtt * ArowL2[4 + s]);
                    float dA2 = exp2f(dtt * ArowL2[8 + s]);
                    float dA3 = exp2f(dtt * ArowL2[12 + s]);
                    h[s] = fmaf(dA0, h[s], dtx * dbA[s]);
                    h[4 + s] = fmaf(dA1, h[4 + s], dtx * dbA[4 + s]);
                    h[8 + s] = fmaf(dA2, h[8 + s], dtx * dbA[8 + s]);
                    h[12 + s] = fmaf(dA3, h[12 + s], dtx * dbA[12 + s]);
                    y0 = fmaf(h[s], dbA[16 + s], y0);
                    y1 = fmaf(h[4 + s], dbA[20 + s], y1);
                    y2 = fmaf(h[8 + s], dbA[24 + s], y2);
                    y3 = fmaf(h[12 + s], dbA[28 + s], y3);
                }
                float y = (y0 + y1) + (y2 + y3);
                yp[(size_t)l * 512] = f2b((y + xv * dsk) * (zv * fast_sig(zv)));
            }
            const float4* nr2 = (const float4*)(dr + (size_t)(l + 2) * 48 + 16);
#pragma unroll
            for (int i = 0; i < 8; i++) ((float4*)dbA)[i] = nr2[i];
            float xv2 = b2f(xp[(size_t)(l + 2) * 512]);
            float zv2 = b2f(zp[(size_t)(l + 2) * 1024]);
            float dt2 = dtp[(size_t)(l + 2) * 512];
            if (l + 1 < SEGLEN) {
                float dtt = dt1;
                float dtx = dtt * xv1;
                float y0 = 0.f, y1 = 0.f, y2 = 0.f, y3 = 0.f;
#pragma unroll
                for (int s = 0; s < 4; s++) {
                    float dA0 = exp2f(dtt * ArowL2[s]);
                    float dA1 = exp2f(dtt * ArowL2[4 + s]);
                    float dA2 = exp2f(dtt * ArowL2[8 + s]);
                    float dA3 = exp2f(dtt * ArowL2[12 + s]);
                    h[s] = fmaf(dA0, h[s], dtx * dbB[s]);
                    h[4 + s] = fmaf(dA1, h[4 + s], dtx * dbB[4 + s]);
                    h[8 + s] = fmaf(dA2, h[8 + s], dtx * dbB[8 + s]);
                    h[12 + s] = fmaf(dA3, h[12 + s], dtx * dbB[12 + s]);
                    y0 = fmaf(h[s], dbB[16 + s], y0);
                    y1 = fmaf(h[4 + s], dbB[20 + s], y1);
                    y2 = fmaf(h[8 + s], dbB[24 + s], y2);
                    y3 = fmaf(h[12 + s], dbB[28 + s], y3);
                }
                float y = (y0 + y1) + (y2 + y3);
                yp[(size_t)(l + 1) * 512] = f2b((y + xv1 * dsk) * (zv1 * fast_sig(zv1)));
            }
            xv = xv2; zv = zv2; dt0 = dt2;
        }
    }
}

extern "C" void kernel_launch(void* const* d_in, const int* in_sizes, int n_in,
                              void* d_out, int out_size, void* d_ws, size_t ws_size,
                              hipStream_t stream) {
    const float* coords   = (const float*)d_in[0];
    const float* emb_W    = (const float*)d_in[1];
    const float* emb_b    = (const float*)d_in[2];
    const float* ln_w     = (const float*)d_in[3];
    const float* ln_b     = (const float*)d_in[4];
    const float* in_W     = (const float*)d_in[5];
    const float* conv_W   = (const float*)d_in[6];
    const float* conv_b   = (const float*)d_in[7];
    const float* xproj_W  = (const float*)d_in[8];
    const float* dtproj_W = (const float*)d_in[9];
    const float* dtproj_b = (const float*)d_in[10];
    const float* A_log    = (const float*)d_in[11];
    const float* D_skip   = (const float*)d_in[12];
    const float* out_W    = (const float*)d_in[13];
    const float* normf_w  = (const float*)d_in[14];
    const float* normf_b  = (const float*)d_in[15];
    const float* head_W   = (const float*)d_in[16];
    float* out = (float*)d_out;

    const int T = NTOK;  // 9600
    float* resid = (float*)d_ws;
    float* dbl   = resid + (size_t)T * D_MODEL;
    float* dts   = dbl + (size_t)T * 48;
    unsigned short* hb     = (unsigned short*)(dts + (size_t)T * D_INNER);
    unsigned short* xzb    = hb + (size_t)T * D_MODEL;
    unsigned short* xcb    = xzb + (size_t)T * 2 * D_INNER;
    unsigned short* yb     = xcb + (size_t)T * D_INNER;
    unsigned short* wb_in  = yb + (size_t)T * D_INNER;
    unsigned short* wb_xp  = wb_in + (size_t)N_LAYERS * 2 * D_INNER * D_MODEL;
    unsigned short* wb_out = wb_xp + (size_t)N_LAYERS * 48 * D_INNER;
    unsigned short* wb_hd  = wb_out + (size_t)N_LAYERS * D_MODEL * D_INNER;

    cvt4_kernel<<<256, 256, 0, stream>>>(
        in_W, wb_in, N_LAYERS * 2 * D_INNER * D_MODEL,
        xproj_W, wb_xp, N_LAYERS * 48 * D_INNER,
        out_W, wb_out, N_LAYERS * D_MODEL * D_INNER,
        head_W, wb_hd, CITY * D_MODEL);

    embed_ln_kernel<<<T, D_MODEL, 0, stream>>>(coords, emb_W, emb_b, ln_w, ln_b, resid, hb);

    for (int i = 0; i < N_LAYERS; i++) {
        // in_proj: (9600,256) x (1024,256)^T -> (9600,1024) bf16
        gemm_mfma<128, 128, false, true><<<dim3(T / 128, 8), 256, 0, stream>>>(
            hb, wb_in + (size_t)i * 2 * D_INNER * D_MODEL, xzb, 2 * D_INNER, D_MODEL);
        // fused conv+silu+xproj: writes xcb (bf16) and dbl (f32)
        conv_xproj_gemm<<<T / 64, 256, 0, stream>>>(
            xzb, conv_W + i * D_INNER * D_CONV, conv_b + i * D_INNER,
            wb_xp + (size_t)i * 48 * D_INNER, xcb, dbl);
        // scan -> yb bf16 (dtt stashed in dts)
        scan_block<<<dim3(8, BATCH), 960, 0, stream>>>(
            xcb, dbl, xzb, A_log + (size_t)i * D_INNER * D_STATE, D_skip + i * D_INNER,
            dtproj_W + (size_t)i * D_INNER * DT_RANK, dtproj_b + i * D_INNER, dts, yb);
        // out_proj + residual + LN (layers 0-2) / RMS (layer 3) fused
        if (i < N_LAYERS - 1)
            gemm_out_ln<false><<<T / 64, 256, 0, stream>>>(
                yb, wb_out + (size_t)i * D_MODEL * D_INNER, resid,
                ln_w + (i + 1) * D_MODEL, ln_b + (i + 1) * D_MODEL, hb);
        else
            gemm_out_ln<true><<<T / 64, 256, 0, stream>>>(
                yb, wb_out + (size_t)i * D_MODEL * D_INNER, resid,
                normf_w, normf_b, hb);
    }

    // head: (9600,256) x (300,256)^T -> (9600,300) f32
    gemm_mfma<64, 64, true, false><<<dim3(T / 64, 5), 256, 0, stream>>>(
        hb, wb_hd, out, CITY, D_MODEL);
}

// Round 18
// 605.926 us; speedup vs baseline: 1.0503x; 1.0503x over previous
//
#include <hip/hip_runtime.h>
#include <hip/hip_bf16.h>
#include <math.h>

#define D_MODEL 256
#define D_INNER 512
#define D_STATE 16
#define D_CONV 4
#define DT_RANK 16
#define N_LAYERS 4
#define CITY 300
#define BATCH 32
#define SEQ 300
#define NTOK (BATCH * SEQ)   // 9600
#define NSEG 15
#define SEGLEN (SEQ / NSEG)  // 20

typedef __attribute__((ext_vector_type(8))) short short8v;
typedef __attribute__((ext_vector_type(4))) float f32x4;

__device__ __forceinline__ float fast_sig(float x) {
    return __builtin_amdgcn_rcpf(1.f + __expf(-x));
}

__device__ __forceinline__ unsigned short f2b(float a) {
    __hip_bfloat16 h = __float2bfloat16(a);
    return *reinterpret_cast<unsigned short*>(&h);
}

__device__ __forceinline__ float b2f(unsigned short u) {
    unsigned int x = ((unsigned int)u) << 16;
    return __uint_as_float(x);
}

// ---------------- all weight conversions, vectorized ----------------
__global__ void cvt4_kernel(const float* __restrict__ s0, unsigned short* __restrict__ d0, int n0,
                            const float* __restrict__ s1, unsigned short* __restrict__ d1, int n1,
                            const float* __restrict__ s2, unsigned short* __restrict__ d2, int n2,
                            const float* __restrict__ s3, unsigned short* __restrict__ d3, int n3) {
    int stride = gridDim.x * blockDim.x;
    int tid = blockIdx.x * blockDim.x + threadIdx.x;
    for (int i = tid; i < n0 / 4; i += stride) {
        float4 v = ((const float4*)s0)[i];
        ushort4 o; o.x = f2b(v.x); o.y = f2b(v.y); o.z = f2b(v.z); o.w = f2b(v.w);
        ((ushort4*)d0)[i] = o;
    }
    for (int i = tid; i < n1 / 4; i += stride) {
        float4 v = ((const float4*)s1)[i];
        ushort4 o; o.x = f2b(v.x); o.y = f2b(v.y); o.z = f2b(v.z); o.w = f2b(v.w);
        ((ushort4*)d1)[i] = o;
    }
    for (int i = tid; i < n2 / 4; i += stride) {
        float4 v = ((const float4*)s2)[i];
        ushort4 o; o.x = f2b(v.x); o.y = f2b(v.y); o.z = f2b(v.z); o.w = f2b(v.w);
        ((ushort4*)d2)[i] = o;
    }
    for (int i = tid; i < n3 / 4; i += stride) {
        float4 v = ((const float4*)s3)[i];
        ushort4 o; o.x = f2b(v.x); o.y = f2b(v.y); o.z = f2b(v.z); o.w = f2b(v.w);
        ((ushort4*)d3)[i] = o;
    }
}

// ---------------- embedding + layer-0 residual init + LN (fused) ----------------
__global__ void embed_ln_kernel(const float* __restrict__ coords,
                                const float* __restrict__ eW,
                                const float* __restrict__ eb,
                                const float* __restrict__ w,
                                const float* __restrict__ b,
                                float* __restrict__ resid,
                                unsigned short* __restrict__ hb) {
    int t = blockIdx.x, d = threadIdx.x;
    float c0 = coords[t * 2 + 0];
    float c1 = coords[t * 2 + 1];
    float r = c0 * eW[d * 2 + 0] + c1 * eW[d * 2 + 1] + eb[d];
    resid[t * D_MODEL + d] = r;
    float s1 = r, s2 = r * r;
#pragma unroll
    for (int m = 1; m < 64; m <<= 1) {
        s1 += __shfl_xor(s1, m);
        s2 += __shfl_xor(s2, m);
    }
    __shared__ float p1[4], p2[4];
    if ((d & 63) == 0) { p1[d >> 6] = s1; p2[d >> 6] = s2; }
    __syncthreads();
    s1 = (p1[0] + p1[1]) + (p1[2] + p1[3]);
    s2 = (p2[0] + p2[1]) + (p2[2] + p2[3]);
    float mean = s1 * (1.f / D_MODEL);
    float var = s2 * (1.f / D_MODEL) - mean * mean;
    hb[t * D_MODEL + d] = f2b((r - mean) * rsqrtf(var + 1e-5f) * w[d] + b[d]);
}

// ------------- bf16-in MFMA GEMM: C[t,n] = sum_k A[t,k] * W[n,k] -------------
template <int BM, int BN, bool GN, bool OB>
__global__ __launch_bounds__(256, 2) void gemm_mfma(const unsigned short* __restrict__ A,
                                                    const unsigned short* __restrict__ W,
                                                    void* __restrict__ C, int N, int K) {
    constexpr int TI = BM / 32;
    constexpr int TJ = BN / 32;
    __shared__ short Als[BM * 32];
    __shared__ short Bls[BN * 32];
    const int tid = threadIdx.x;
    const int lane = tid & 63, wid = tid >> 6;
    const int wr = wid >> 1, wc = wid & 1;
    const int t0 = blockIdx.x * BM, n0 = blockIdx.y * BN;
    f32x4 acc[TI][TJ] = {};

    for (int k0 = 0; k0 < K; k0 += 32) {
#pragma unroll
        for (int it = 0; it < BM / 64; ++it) {
            int s = tid + it * 256;
            int m = s >> 2, q = s & 3;
            uint4 p = *(const uint4*)(A + (size_t)(t0 + m) * K + k0 + q * 8);
            *(uint4*)&Als[(((m >> 4) * 4 + q) * 16 + (m & 15)) * 8] = p;
        }
#pragma unroll
        for (int it = 0; it < BN / 64; ++it) {
            int s = tid + it * 256;
            int n = s >> 2, q = s & 3;
            int nrow = n0 + n;
            uint4 p = make_uint4(0u, 0u, 0u, 0u);
            if (!GN || nrow < N)
                p = *(const uint4*)(W + (size_t)nrow * K + k0 + q * 8);
            *(uint4*)&Bls[(((n >> 4) * 4 + q) * 16 + (n & 15)) * 8] = p;
        }
        __syncthreads();
        short8v af[TI], bf[TJ];
#pragma unroll
        for (int i = 0; i < TI; i++)
            af[i] = *(const short8v*)&Als[(wr * TI + i) * 512 + lane * 8];
#pragma unroll
        for (int j = 0; j < TJ; j++)
            bf[j] = *(const short8v*)&Bls[(wc * TJ + j) * 512 + lane * 8];
#pragma unroll
        for (int i = 0; i < TI; i++)
#pragma unroll
            for (int j = 0; j < TJ; j++)
                acc[i][j] = __builtin_amdgcn_mfma_f32_16x16x32_bf16(
                    af[i], bf[j], acc[i][j], 0, 0, 0);
        __syncthreads();
    }
    const int rq = lane >> 4, cn = lane & 15;
#pragma unroll
    for (int i = 0; i < TI; i++) {
        int trow = t0 + wr * (BM / 2) + i * 16 + rq * 4;
#pragma unroll
        for (int j = 0; j < TJ; j++) {
            int ncol = n0 + wc * (BN / 2) + j * 16 + cn;
            if (!GN || ncol < N) {
#pragma unroll
                for (int reg = 0; reg < 4; reg++) {
                    if constexpr (OB)
                        ((unsigned short*)C)[(size_t)(trow + reg) * N + ncol] =
                            f2b(acc[i][j][reg]);
                    else
                        ((float*)C)[(size_t)(trow + reg) * N + ncol] = acc[i][j][reg];
                }
            }
        }
    }
}

// ------------- out_proj GEMM + residual add + LN/RMS fused epilogue -------------
template <bool RMS>
__global__ __launch_bounds__(256, 2) void gemm_out_ln(const unsigned short* __restrict__ A,
                                                      const unsigned short* __restrict__ W,
                                                      float* __restrict__ resid,
                                                      const float* __restrict__ w,
                                                      const float* __restrict__ b,
                                                      unsigned short* __restrict__ hb) {
    constexpr int TI = 2, TJ = 8;
    const int K = D_INNER;
    __shared__ short Als[64 * 32];
    __shared__ short Bls[256 * 32];
    __shared__ float rs1[2][64], rs2[2][64];
    const int tid = threadIdx.x;
    const int lane = tid & 63, wid = tid >> 6;
    const int wr = wid >> 1, wc = wid & 1;
    const int t0 = blockIdx.x * 64;
    f32x4 acc[TI][TJ] = {};

    for (int k0 = 0; k0 < K; k0 += 32) {
        {
            int s = tid;
            int m = s >> 2, q = s & 3;
            uint4 p = *(const uint4*)(A + (size_t)(t0 + m) * K + k0 + q * 8);
            *(uint4*)&Als[(((m >> 4) * 4 + q) * 16 + (m & 15)) * 8] = p;
        }
#pragma unroll
        for (int it = 0; it < 4; ++it) {
            int s = tid + it * 256;
            int n = s >> 2, q = s & 3;
            uint4 p = *(const uint4*)(W + (size_t)n * K + k0 + q * 8);
            *(uint4*)&Bls[(((n >> 4) * 4 + q) * 16 + (n & 15)) * 8] = p;
        }
        __syncthreads();
        short8v af[TI], bf[TJ];
#pragma unroll
        for (int i = 0; i < TI; i++)
            af[i] = *(const short8v*)&Als[(wr * TI + i) * 512 + lane * 8];
#pragma unroll
        for (int j = 0; j < TJ; j++)
            bf[j] = *(const short8v*)&Bls[(wc * TJ + j) * 512 + lane * 8];
#pragma unroll
        for (int i = 0; i < TI; i++)
#pragma unroll
            for (int j = 0; j < TJ; j++)
                acc[i][j] = __builtin_amdgcn_mfma_f32_16x16x32_bf16(
                    af[i], bf[j], acc[i][j], 0, 0, 0);
        __syncthreads();
    }
    const int rq = lane >> 4, cn = lane & 15;
    float s1p[TI][4], s2p[TI][4];
#pragma unroll
    for (int i = 0; i < TI; i++) {
        int trow = t0 + wr * 32 + i * 16 + rq * 4;
#pragma unroll
        for (int reg = 0; reg < 4; reg++) { s1p[i][reg] = 0.f; s2p[i][reg] = 0.f; }
#pragma unroll
        for (int j = 0; j < TJ; j++) {
            int c = wc * 128 + j * 16 + cn;
#pragma unroll
            for (int reg = 0; reg < 4; reg++) {
                float rv = acc[i][j][reg] + resid[(size_t)(trow + reg) * D_MODEL + c];
                acc[i][j][reg] = rv;
                s1p[i][reg] += rv;
                s2p[i][reg] = fmaf(rv, rv, s2p[i][reg]);
            }
        }
    }
#pragma unroll
    for (int m = 1; m < 16; m <<= 1) {
#pragma unroll
        for (int i = 0; i < TI; i++)
#pragma unroll
            for (int reg = 0; reg < 4; reg++) {
                s1p[i][reg] += __shfl_xor(s1p[i][reg], m);
                s2p[i][reg] += __shfl_xor(s2p[i][reg], m);
            }
    }
    if (cn == 0) {
#pragma unroll
        for (int i = 0; i < TI; i++)
#pragma unroll
            for (int reg = 0; reg < 4; reg++) {
                int rloc = wr * 32 + i * 16 + rq * 4 + reg;
                rs1[wc][rloc] = s1p[i][reg];
                rs2[wc][rloc] = s2p[i][reg];
            }
    }
    __syncthreads();
    float wv[TJ], bv[TJ];
#pragma unroll
    for (int j = 0; j < TJ; j++) {
        int c = wc * 128 + j * 16 + cn;
        wv[j] = w[c];
        bv[j] = b[c];
    }
#pragma unroll
    for (int i = 0; i < TI; i++) {
        int trow = t0 + wr * 32 + i * 16 + rq * 4;
#pragma unroll
        for (int reg = 0; reg < 4; reg++) {
            int rloc = wr * 32 + i * 16 + rq * 4 + reg;
            float S1 = rs1[0][rloc] + rs1[1][rloc];
            float S2 = rs2[0][rloc] + rs2[1][rloc];
            float mean, rstd;
            if constexpr (RMS) {
                mean = 0.f;
                rstd = rsqrtf(S2 * (1.f / D_MODEL) + 1e-5f);
            } else {
                mean = S1 * (1.f / D_MODEL);
                float var = S2 * (1.f / D_MODEL) - mean * mean;
                rstd = rsqrtf(var + 1e-5f);
            }
#pragma unroll
            for (int j = 0; j < TJ; j++) {
                int c = wc * 128 + j * 16 + cn;
                float rv = acc[i][j][reg];
                hb[(size_t)(trow + reg) * D_MODEL + c] =
                    f2b((rv - mean) * rstd * wv[j] + bv[j]);
                if constexpr (!RMS)
                    resid[(size_t)(trow + reg) * D_MODEL + c] = rv;
            }
        }
    }
}

// ------------- causal conv (k=4) + bias + SiLU; bf16 in, bf16 out -------------
__global__ void conv_silu_kernel(const unsigned short* __restrict__ xzb,
                                 const float* __restrict__ cW,
                                 const float* __restrict__ cb,
                                 unsigned short* __restrict__ xcb) {
    int idx = blockIdx.x * blockDim.x + threadIdx.x;  // 4-channel groups
    int d4 = (idx & 127) * 4;
    int t = idx >> 7;
    int l = t % SEQ;
    float4 acc = *(const float4*)(cb + d4);
    float4 wA = *(const float4*)(cW + (d4 + 0) * 4);
    float4 wB = *(const float4*)(cW + (d4 + 1) * 4);
    float4 wC = *(const float4*)(cW + (d4 + 2) * 4);
    float4 wD = *(const float4*)(cW + (d4 + 3) * 4);
#pragma unroll
    for (int k = 0; k < D_CONV; k++) {
        int ll = l - 3 + k;
        if (ll >= 0) {
            ushort4 u = *(const ushort4*)(xzb + (size_t)(t - 3 + k) * 1024 + d4);
            float wa = (k == 0) ? wA.x : (k == 1) ? wA.y : (k == 2) ? wA.z : wA.w;
            float wb = (k == 0) ? wB.x : (k == 1) ? wB.y : (k == 2) ? wB.z : wB.w;
            float wc = (k == 0) ? wC.x : (k == 1) ? wC.y : (k == 2) ? wC.z : wC.w;
            float wd = (k == 0) ? wD.x : (k == 1) ? wD.y : (k == 2) ? wD.z : wD.w;
            acc.x = fmaf(b2f(u.x), wa, acc.x);
            acc.y = fmaf(b2f(u.y), wb, acc.y);
            acc.z = fmaf(b2f(u.z), wc, acc.z);
            acc.w = fmaf(b2f(u.w), wd, acc.w);
        }
    }
    ushort4 ob;
    ob.x = f2b(acc.x * fast_sig(acc.x));
    ob.y = f2b(acc.y * fast_sig(acc.y));
    ob.z = f2b(acc.z * fast_sig(acc.z));
    ob.w = f2b(acc.w * fast_sig(acc.w));
    *(ushort4*)(xcb + (size_t)t * 512 + d4) = ob;
}

// ========== scan v7: phase-3 via closed-form correction ==========
// Phase1: local scan from h=0 over full 48-float rows; emits to scratch per step:
//   p = (y_loc + x*dsk)*g, g = z*sig(z), cum = prefix-sum of dt (inclusive).
// Phase2: in-LDS prefix combine (unchanged) -> lh holds segment-initial H0.
// Phase3 (dependency-free): out_l = p_l + g_l * sum_s C_l[s]*exp2(A_s*cum_l)*H0[s].
__global__ __launch_bounds__(960) void scan_block(
    const unsigned short* __restrict__ xcb, const float* __restrict__ dbl,
    const unsigned short* __restrict__ xzb,
    const float* __restrict__ A_log, const float* __restrict__ Dskip,
    const float* __restrict__ dtW, const float* __restrict__ dtb,
    float* __restrict__ pbuf, float* __restrict__ gbuf, float* __restrict__ cbuf,
    unsigned short* __restrict__ yb) {
    __shared__ float lh[NSEG * D_STATE * 64];
    __shared__ float lsd[NSEG * 64];
    const int dg = blockIdx.x, b = blockIdx.y;
    const int tid = threadIdx.x;
    const int lane = tid & 63;
    const int seg = __builtin_amdgcn_readfirstlane(tid >> 6);  // wave-uniform
    const int d = (dg << 6) + lane;
    const float LOG2E = 1.44269504088896340736f;
    float ArowL2[D_STATE], dWr[DT_RANK];
#pragma unroll
    for (int s4 = 0; s4 < 4; s4++) {
        float4 v = *(const float4*)(A_log + (size_t)d * D_STATE + s4 * 4);
        ArowL2[s4 * 4 + 0] = -__expf(v.x) * LOG2E;
        ArowL2[s4 * 4 + 1] = -__expf(v.y) * LOG2E;
        ArowL2[s4 * 4 + 2] = -__expf(v.z) * LOG2E;
        ArowL2[s4 * 4 + 3] = -__expf(v.w) * LOG2E;
        float4 w = *(const float4*)(dtW + (size_t)d * DT_RANK + s4 * 4);
        dWr[s4 * 4 + 0] = w.x; dWr[s4 * 4 + 1] = w.y;
        dWr[s4 * 4 + 2] = w.z; dWr[s4 * 4 + 3] = w.w;
    }
    const float dtbv = dtb[d], dsk = Dskip[d];
    const size_t tb = (size_t)b * SEQ + (size_t)seg * SEGLEN;
    const float* __restrict__ dr = dbl + tb * 48;
    const unsigned short* __restrict__ xp = xcb + tb * 512 + d;
    const unsigned short* __restrict__ zp = xzb + tb * 1024 + 512 + d;
    float* __restrict__ pp = pbuf + tb * 512 + d;
    float* __restrict__ gp = gbuf + tb * 512 + d;
    float* __restrict__ cp = cbuf + tb * 512 + d;
    unsigned short* __restrict__ yp = yb + tb * 512 + d;

    // ---------------- phase 1: local scan from h=0; emit p/g/cum ----------------
    {
        float h[D_STATE];
#pragma unroll
        for (int s = 0; s < D_STATE; s++) h[s] = 0.f;
        float cum = 0.f;
        float dbA[48], dbB[48];
#pragma unroll
        for (int i = 0; i < 12; i++) ((float4*)dbA)[i] = ((const float4*)dr)[i];
        float xv = b2f(xp[0]), zv = b2f(zp[0]);
        for (int l = 0; l < SEGLEN; l += 2) {
            const float4* nr1 = (const float4*)(dr + (size_t)(l + 1) * 48);
#pragma unroll
            for (int i = 0; i < 12; i++) ((float4*)dbB)[i] = nr1[i];
            float xv1 = b2f(xp[(size_t)(l + 1) * 512]);
            float zv1 = b2f(zp[(size_t)(l + 1) * 1024]);
            {
                float a0 = dtbv, a1 = 0.f, a2 = 0.f, a3 = 0.f;
#pragma unroll
                for (int r = 0; r < 4; r++) {
                    a0 = fmaf(dbA[r], dWr[r], a0);
                    a1 = fmaf(dbA[4 + r], dWr[4 + r], a1);
                    a2 = fmaf(dbA[8 + r], dWr[8 + r], a2);
                    a3 = fmaf(dbA[12 + r], dWr[12 + r], a3);
                }
                float acc = (a0 + a1) + (a2 + a3);
                float dtt = fmaxf(acc, 0.f) + __logf(1.f + __expf(-fabsf(acc)));
                cum += dtt;
                float dtx = dtt * xv;
                float y0 = 0.f, y1 = 0.f, y2 = 0.f, y3 = 0.f;
#pragma unroll
                for (int s = 0; s < 4; s++) {
                    float dA0 = exp2f(dtt * ArowL2[s]);
                    float dA1 = exp2f(dtt * ArowL2[4 + s]);
                    float dA2 = exp2f(dtt * ArowL2[8 + s]);
                    float dA3 = exp2f(dtt * ArowL2[12 + s]);
                    h[s] = fmaf(dA0, h[s], dtx * dbA[16 + s]);
                    h[4 + s] = fmaf(dA1, h[4 + s], dtx * dbA[20 + s]);
                    h[8 + s] = fmaf(dA2, h[8 + s], dtx * dbA[24 + s]);
                    h[12 + s] = fmaf(dA3, h[12 + s], dtx * dbA[28 + s]);
                    y0 = fmaf(h[s], dbA[32 + s], y0);
                    y1 = fmaf(h[4 + s], dbA[36 + s], y1);
                    y2 = fmaf(h[8 + s], dbA[40 + s], y2);
                    y3 = fmaf(h[12 + s], dbA[44 + s], y3);
                }
                float y = (y0 + y1) + (y2 + y3);
                float g = zv * fast_sig(zv);
                pp[(size_t)l * 512] = (y + xv * dsk) * g;
                gp[(size_t)l * 512] = g;
                cp[(size_t)l * 512] = cum;
            }
            const float4* nr2 = (const float4*)(dr + (size_t)(l + 2) * 48);
#pragma unroll
            for (int i = 0; i < 12; i++) ((float4*)dbA)[i] = nr2[i];
            float xv2 = b2f(xp[(size_t)(l + 2) * 512]);
            float zv2 = b2f(zp[(size_t)(l + 2) * 1024]);
            if (l + 1 < SEGLEN) {
                float a0 = dtbv, a1 = 0.f, a2 = 0.f, a3 = 0.f;
#pragma unroll
                for (int r = 0; r < 4; r++) {
                    a0 = fmaf(dbB[r], dWr[r], a0);
                    a1 = fmaf(dbB[4 + r], dWr[4 + r], a1);
                    a2 = fmaf(dbB[8 + r], dWr[8 + r], a2);
                    a3 = fmaf(dbB[12 + r], dWr[12 + r], a3);
                }
                float acc = (a0 + a1) + (a2 + a3);
                float dtt = fmaxf(acc, 0.f) + __logf(1.f + __expf(-fabsf(acc)));
                cum += dtt;
                float dtx = dtt * xv1;
                float y0 = 0.f, y1 = 0.f, y2 = 0.f, y3 = 0.f;
#pragma unroll
                for (int s = 0; s < 4; s++) {
                    float dA0 = exp2f(dtt * ArowL2[s]);
                    float dA1 = exp2f(dtt * ArowL2[4 + s]);
                    float dA2 = exp2f(dtt * ArowL2[8 + s]);
                    float dA3 = exp2f(dtt * ArowL2[12 + s]);
                    h[s] = fmaf(dA0, h[s], dtx * dbB[16 + s]);
                    h[4 + s] = fmaf(dA1, h[4 + s], dtx * dbB[20 + s]);
                    h[8 + s] = fmaf(dA2, h[8 + s], dtx * dbB[24 + s]);
                    h[12 + s] = fmaf(dA3, h[12 + s], dtx * dbB[28 + s]);
                    y0 = fmaf(h[s], dbB[32 + s], y0);
                    y1 = fmaf(h[4 + s], dbB[36 + s], y1);
                    y2 = fmaf(h[8 + s], dbB[40 + s], y2);
                    y3 = fmaf(h[12 + s], dbB[44 + s], y3);
                }
                float y = (y0 + y1) + (y2 + y3);
                float g = zv1 * fast_sig(zv1);
                pp[(size_t)(l + 1) * 512] = (y + xv1 * dsk) * g;
                gp[(size_t)(l + 1) * 512] = g;
                cp[(size_t)(l + 1) * 512] = cum;
            }
            xv = xv2; zv = zv2;
        }
#pragma unroll
        for (int s = 0; s < D_STATE; s++) lh[(seg * D_STATE + s) * 64 + lane] = h[s];
        lsd[seg * 64 + lane] = cum;
    }
    __syncthreads();
    // ---------------- phase 2: in-LDS prefix combine ----------------
    for (int it = tid; it < D_STATE * 64; it += 960) {
        int ch = it & 63, s = it >> 6;
        float As2 = -__expf(A_log[(size_t)((dg << 6) + ch) * D_STATE + s]) * LOG2E;
        float H = 0.f;
        for (int sg = 0; sg < NSEG; sg++) {
            float hl = lh[(sg * D_STATE + s) * 64 + ch];
            float sd = lsd[sg * 64 + ch];
            lh[(sg * D_STATE + s) * 64 + ch] = H;
            H = fmaf(exp2f(As2 * sd), H, hl);
        }
    }
    __syncthreads();
    // ---------------- phase 3: dependency-free correction ----------------
    {
        float H0[D_STATE];
#pragma unroll
        for (int s = 0; s < D_STATE; s++) H0[s] = lh[(seg * D_STATE + s) * 64 + lane];
        float cA[16], cB[16];
#pragma unroll
        for (int i = 0; i < 4; i++) ((float4*)cA)[i] = ((const float4*)(dr + 32))[i];
        float pv = pp[0], gv = gp[0], cd = cp[0];
        for (int l = 0; l < SEGLEN; l += 2) {
            const float4* nr1 = (const float4*)(dr + (size_t)(l + 1) * 48 + 32);
#pragma unroll
            for (int i = 0; i < 4; i++) ((float4*)cB)[i] = nr1[i];
            float pv1 = pp[(size_t)(l + 1) * 512];
            float gv1 = gp[(size_t)(l + 1) * 512];
            float cd1 = cp[(size_t)(l + 1) * 512];
            {
                float y0 = 0.f, y1 = 0.f, y2 = 0.f, y3 = 0.f;
#pragma unroll
                for (int s = 0; s < 4; s++) {
                    y0 = fmaf(cA[s] * H0[s], exp2f(cd * ArowL2[s]), y0);
                    y1 = fmaf(cA[4 + s] * H0[4 + s], exp2f(cd * ArowL2[4 + s]), y1);
                    y2 = fmaf(cA[8 + s] * H0[8 + s], exp2f(cd * ArowL2[8 + s]), y2);
                    y3 = fmaf(cA[12 + s] * H0[12 + s], exp2f(cd * ArowL2[12 + s]), y3);
                }
                float corr = (y0 + y1) + (y2 + y3);
                yp[(size_t)l * 512] = f2b(fmaf(gv, corr, pv));
            }
            const float4* nr2 = (const float4*)(dr + (size_t)(l + 2) * 48 + 32);
#pragma unroll
            for (int i = 0; i < 4; i++) ((float4*)cA)[i] = nr2[i];
            float pv2 = pp[(size_t)(l + 2) * 512];
            float gv2 = gp[(size_t)(l + 2) * 512];
            float cd2 = cp[(size_t)(l + 2) * 512];
            if (l + 1 < SEGLEN) {
                float y0 = 0.f, y1 = 0.f, y2 = 0.f, y3 = 0.f;
#pragma unroll
                for (int s = 0; s < 4; s++) {
                    y0 = fmaf(cB[s] * H0[s], exp2f(cd1 * ArowL2[s]), y0);
                    y1 = fmaf(cB[4 + s] * H0[4 + s], exp2f(cd1 * ArowL2[4 + s]), y1);
                    y2 = fmaf(cB[8 + s] * H0[8 + s], exp2f(cd1 * ArowL2[8 + s]), y2);
                    y3 = fmaf(cB[12 + s] * H0[12 + s], exp2f(cd1 * ArowL2[12 + s]), y3);
                }
                float corr = (y0 + y1) + (y2 + y3);
                yp[(size_t)(l + 1) * 512] = f2b(fmaf(gv1, corr, pv1));
            }
            pv = pv2; gv = gv2; cd = cd2;
        }
    }
}

extern "C" void kernel_launch(void* const* d_in, const int* in_sizes, int n_in,
                              void* d_out, int out_size, void* d_ws, size_t ws_size,
                              hipStream_t stream) {
    const float* coords   = (const float*)d_in[0];
    const float* emb_W    = (const float*)d_in[1];
    const float* emb_b    = (const float*)d_in[2];
    const float* ln_w     = (const float*)d_in[3];
    const float* ln_b     = (const float*)d_in[4];
    const float* in_W     = (const float*)d_in[5];
    const float* conv_W   = (const float*)d_in[6];
    const float* conv_b   = (const float*)d_in[7];
    const float* xproj_W  = (const float*)d_in[8];
    const float* dtproj_W = (const float*)d_in[9];
    const float* dtproj_b = (const float*)d_in[10];
    const float* A_log    = (const float*)d_in[11];
    const float* D_skip   = (const float*)d_in[12];
    const float* out_W    = (const float*)d_in[13];
    const float* normf_w  = (const float*)d_in[14];
    const float* normf_b  = (const float*)d_in[15];
    const float* head_W   = (const float*)d_in[16];
    float* out = (float*)d_out;

    const int T = NTOK;  // 9600
    float* resid = (float*)d_ws;
    float* dbl   = resid + (size_t)T * D_MODEL;
    float* pbuf  = dbl + (size_t)T * 48;
    float* gbuf  = pbuf + (size_t)T * D_INNER;
    float* cbuf  = gbuf + (size_t)T * D_INNER;
    unsigned short* hb     = (unsigned short*)(cbuf + (size_t)T * D_INNER);
    unsigned short* xzb    = hb + (size_t)T * D_MODEL;
    unsigned short* xcb    = xzb + (size_t)T * 2 * D_INNER;
    unsigned short* yb     = xcb + (size_t)T * D_INNER;
    unsigned short* wb_in  = yb + (size_t)T * D_INNER;
    unsigned short* wb_xp  = wb_in + (size_t)N_LAYERS * 2 * D_INNER * D_MODEL;
    unsigned short* wb_out = wb_xp + (size_t)N_LAYERS * 48 * D_INNER;
    unsigned short* wb_hd  = wb_out + (size_t)N_LAYERS * D_MODEL * D_INNER;

    cvt4_kernel<<<256, 256, 0, stream>>>(
        in_W, wb_in, N_LAYERS * 2 * D_INNER * D_MODEL,
        xproj_W, wb_xp, N_LAYERS * 48 * D_INNER,
        out_W, wb_out, N_LAYERS * D_MODEL * D_INNER,
        head_W, wb_hd, CITY * D_MODEL);

    embed_ln_kernel<<<T, D_MODEL, 0, stream>>>(coords, emb_W, emb_b, ln_w, ln_b, resid, hb);

    for (int i = 0; i < N_LAYERS; i++) {
        // in_proj: (9600,256) x (1024,256)^T -> (9600,1024) bf16
        gemm_mfma<128, 128, false, true><<<dim3(T / 128, 8), 256, 0, stream>>>(
            hb, wb_in + (size_t)i * 2 * D_INNER * D_MODEL, xzb, 2 * D_INNER, D_MODEL);
        conv_silu_kernel<<<T * 128 / 256, 256, 0, stream>>>(
            xzb, conv_W + i * D_INNER * D_CONV, conv_b + i * D_INNER, xcb);
        // xproj: (9600,512) x (48,512)^T -> (9600,48) f32
        gemm_mfma<64, 64, true, false><<<dim3(T / 64, 1), 256, 0, stream>>>(
            xcb, wb_xp + (size_t)i * 48 * D_INNER, dbl, 48, D_INNER);
        // scan v7 -> yb bf16
        scan_block<<<dim3(8, BATCH), 960, 0, stream>>>(
            xcb, dbl, xzb, A_log + (size_t)i * D_INNER * D_STATE, D_skip + i * D_INNER,
            dtproj_W + (size_t)i * D_INNER * DT_RANK, dtproj_b + i * D_INNER,
            pbuf, gbuf, cbuf, yb);
        // out_proj + residual + LN (layers 0-2) / RMS (layer 3) fused
        if (i < N_LAYERS - 1)
            gemm_out_ln<false><<<T / 64, 256, 0, stream>>>(
                yb, wb_out + (size_t)i * D_MODEL * D_INNER, resid,
                ln_w + (i + 1) * D_MODEL, ln_b + (i + 1) * D_MODEL, hb);
        else
            gemm_out_ln<true><<<T / 64, 256, 0, stream>>>(
                yb, wb_out + (size_t)i * D_MODEL * D_INNER, resid,
                normf_w, normf_b, hb);
    }

    // head: (9600,256) x (300,256)^T -> (9600,300) f32
    gemm_mfma<64, 64, true, false><<<dim3(T / 64, 5), 256, 0, stream>>>(
        hb, wb_hd, out, CITY, D_MODEL);
}

// Round 19
// 589.266 us; speedup vs baseline: 1.0800x; 1.0283x over previous
//
#include <hip/hip_runtime.h>
#include <hip/hip_bf16.h>
#include <math.h>

#define D_MODEL 256
#define D_INNER 512
#define D_STATE 16
#define D_CONV 4
#define DT_RANK 16
#define N_LAYERS 4
#define CITY 300
#define BATCH 32
#define SEQ 300
#define NTOK (BATCH * SEQ)   // 9600
#define NSEG 15
#define SEGLEN (SEQ / NSEG)  // 20

typedef __attribute__((ext_vector_type(8))) short short8v;
typedef __attribute__((ext_vector_type(4))) float f32x4;

__device__ __forceinline__ float fast_sig(float x) {
    return __builtin_amdgcn_rcpf(1.f + __expf(-x));
}

__device__ __forceinline__ unsigned short f2b(float a) {
    __hip_bfloat16 h = __float2bfloat16(a);
    return *reinterpret_cast<unsigned short*>(&h);
}

__device__ __forceinline__ float b2f(unsigned short u) {
    unsigned int x = ((unsigned int)u) << 16;
    return __uint_as_float(x);
}

// ---------------- all weight conversions, vectorized ----------------
__global__ void cvt4_kernel(const float* __restrict__ s0, unsigned short* __restrict__ d0, int n0,
                            const float* __restrict__ s1, unsigned short* __restrict__ d1, int n1,
                            const float* __restrict__ s2, unsigned short* __restrict__ d2, int n2,
                            const float* __restrict__ s3, unsigned short* __restrict__ d3, int n3) {
    int stride = gridDim.x * blockDim.x;
    int tid = blockIdx.x * blockDim.x + threadIdx.x;
    for (int i = tid; i < n0 / 4; i += stride) {
        float4 v = ((const float4*)s0)[i];
        ushort4 o; o.x = f2b(v.x); o.y = f2b(v.y); o.z = f2b(v.z); o.w = f2b(v.w);
        ((ushort4*)d0)[i] = o;
    }
    for (int i = tid; i < n1 / 4; i += stride) {
        float4 v = ((const float4*)s1)[i];
        ushort4 o; o.x = f2b(v.x); o.y = f2b(v.y); o.z = f2b(v.z); o.w = f2b(v.w);
        ((ushort4*)d1)[i] = o;
    }
    for (int i = tid; i < n2 / 4; i += stride) {
        float4 v = ((const float4*)s2)[i];
        ushort4 o; o.x = f2b(v.x); o.y = f2b(v.y); o.z = f2b(v.z); o.w = f2b(v.w);
        ((ushort4*)d2)[i] = o;
    }
    for (int i = tid; i < n3 / 4; i += stride) {
        float4 v = ((const float4*)s3)[i];
        ushort4 o; o.x = f2b(v.x); o.y = f2b(v.y); o.z = f2b(v.z); o.w = f2b(v.w);
        ((ushort4*)d3)[i] = o;
    }
}

// ---------------- embedding + layer-0 residual init + LN (fused) ----------------
__global__ void embed_ln_kernel(const float* __restrict__ coords,
                                const float* __restrict__ eW,
                                const float* __restrict__ eb,
                                const float* __restrict__ w,
                                const float* __restrict__ b,
                                float* __restrict__ resid,
                                unsigned short* __restrict__ hb) {
    int t = blockIdx.x, d = threadIdx.x;
    float c0 = coords[t * 2 + 0];
    float c1 = coords[t * 2 + 1];
    float r = c0 * eW[d * 2 + 0] + c1 * eW[d * 2 + 1] + eb[d];
    resid[t * D_MODEL + d] = r;
    float s1 = r, s2 = r * r;
#pragma unroll
    for (int m = 1; m < 64; m <<= 1) {
        s1 += __shfl_xor(s1, m);
        s2 += __shfl_xor(s2, m);
    }
    __shared__ float p1[4], p2[4];
    if ((d & 63) == 0) { p1[d >> 6] = s1; p2[d >> 6] = s2; }
    __syncthreads();
    s1 = (p1[0] + p1[1]) + (p1[2] + p1[3]);
    s2 = (p2[0] + p2[1]) + (p2[2] + p2[3]);
    float mean = s1 * (1.f / D_MODEL);
    float var = s2 * (1.f / D_MODEL) - mean * mean;
    hb[t * D_MODEL + d] = f2b((r - mean) * rsqrtf(var + 1e-5f) * w[d] + b[d]);
}

// ------------- bf16-in MFMA GEMM: C[t,n] = sum_k A[t,k] * W[n,k] -------------
template <int BM, int BN, bool GN, bool OB>
__global__ __launch_bounds__(256, 2) void gemm_mfma(const unsigned short* __restrict__ A,
                                                    const unsigned short* __restrict__ W,
                                                    void* __restrict__ C, int N, int K) {
    constexpr int TI = BM / 32;
    constexpr int TJ = BN / 32;
    __shared__ short Als[BM * 32];
    __shared__ short Bls[BN * 32];
    const int tid = threadIdx.x;
    const int lane = tid & 63, wid = tid >> 6;
    const int wr = wid >> 1, wc = wid & 1;
    const int t0 = blockIdx.x * BM, n0 = blockIdx.y * BN;
    f32x4 acc[TI][TJ] = {};

    for (int k0 = 0; k0 < K; k0 += 32) {
#pragma unroll
        for (int it = 0; it < BM / 64; ++it) {
            int s = tid + it * 256;
            int m = s >> 2, q = s & 3;
            uint4 p = *(const uint4*)(A + (size_t)(t0 + m) * K + k0 + q * 8);
            *(uint4*)&Als[(((m >> 4) * 4 + q) * 16 + (m & 15)) * 8] = p;
        }
#pragma unroll
        for (int it = 0; it < BN / 64; ++it) {
            int s = tid + it * 256;
            int n = s >> 2, q = s & 3;
            int nrow = n0 + n;
            uint4 p = make_uint4(0u, 0u, 0u, 0u);
            if (!GN || nrow < N)
                p = *(const uint4*)(W + (size_t)nrow * K + k0 + q * 8);
            *(uint4*)&Bls[(((n >> 4) * 4 + q) * 16 + (n & 15)) * 8] = p;
        }
        __syncthreads();
        short8v af[TI], bf[TJ];
#pragma unroll
        for (int i = 0; i < TI; i++)
            af[i] = *(const short8v*)&Als[(wr * TI + i) * 512 + lane * 8];
#pragma unroll
        for (int j = 0; j < TJ; j++)
            bf[j] = *(const short8v*)&Bls[(wc * TJ + j) * 512 + lane * 8];
#pragma unroll
        for (int i = 0; i < TI; i++)
#pragma unroll
            for (int j = 0; j < TJ; j++)
                acc[i][j] = __builtin_amdgcn_mfma_f32_16x16x32_bf16(
                    af[i], bf[j], acc[i][j], 0, 0, 0);
        __syncthreads();
    }
    const int rq = lane >> 4, cn = lane & 15;
#pragma unroll
    for (int i = 0; i < TI; i++) {
        int trow = t0 + wr * (BM / 2) + i * 16 + rq * 4;
#pragma unroll
        for (int j = 0; j < TJ; j++) {
            int ncol = n0 + wc * (BN / 2) + j * 16 + cn;
            if (!GN || ncol < N) {
#pragma unroll
                for (int reg = 0; reg < 4; reg++) {
                    if constexpr (OB)
                        ((unsigned short*)C)[(size_t)(trow + reg) * N + ncol] =
                            f2b(acc[i][j][reg]);
                    else
                        ((float*)C)[(size_t)(trow + reg) * N + ncol] = acc[i][j][reg];
                }
            }
        }
    }
}

// ------------- out_proj GEMM + residual add + LN/RMS fused epilogue -------------
template <bool RMS>
__global__ __launch_bounds__(256, 2) void gemm_out_ln(const unsigned short* __restrict__ A,
                                                      const unsigned short* __restrict__ W,
                                                      float* __restrict__ resid,
                                                      const float* __restrict__ w,
                                                      const float* __restrict__ b,
                                                      unsigned short* __restrict__ hb) {
    constexpr int TI = 2, TJ = 8;
    const int K = D_INNER;
    __shared__ short Als[64 * 32];
    __shared__ short Bls[256 * 32];
    __shared__ float rs1[2][64], rs2[2][64];
    const int tid = threadIdx.x;
    const int lane = tid & 63, wid = tid >> 6;
    const int wr = wid >> 1, wc = wid & 1;
    const int t0 = blockIdx.x * 64;
    f32x4 acc[TI][TJ] = {};

    for (int k0 = 0; k0 < K; k0 += 32) {
        {
            int s = tid;
            int m = s >> 2, q = s & 3;
            uint4 p = *(const uint4*)(A + (size_t)(t0 + m) * K + k0 + q * 8);
            *(uint4*)&Als[(((m >> 4) * 4 + q) * 16 + (m & 15)) * 8] = p;
        }
#pragma unroll
        for (int it = 0; it < 4; ++it) {
            int s = tid + it * 256;
            int n = s >> 2, q = s & 3;
            uint4 p = *(const uint4*)(W + (size_t)n * K + k0 + q * 8);
            *(uint4*)&Bls[(((n >> 4) * 4 + q) * 16 + (n & 15)) * 8] = p;
        }
        __syncthreads();
        short8v af[TI], bf[TJ];
#pragma unroll
        for (int i = 0; i < TI; i++)
            af[i] = *(const short8v*)&Als[(wr * TI + i) * 512 + lane * 8];
#pragma unroll
        for (int j = 0; j < TJ; j++)
            bf[j] = *(const short8v*)&Bls[(wc * TJ + j) * 512 + lane * 8];
#pragma unroll
        for (int i = 0; i < TI; i++)
#pragma unroll
            for (int j = 0; j < TJ; j++)
                acc[i][j] = __builtin_amdgcn_mfma_f32_16x16x32_bf16(
                    af[i], bf[j], acc[i][j], 0, 0, 0);
        __syncthreads();
    }
    const int rq = lane >> 4, cn = lane & 15;
    float s1p[TI][4], s2p[TI][4];
#pragma unroll
    for (int i = 0; i < TI; i++) {
        int trow = t0 + wr * 32 + i * 16 + rq * 4;
#pragma unroll
        for (int reg = 0; reg < 4; reg++) { s1p[i][reg] = 0.f; s2p[i][reg] = 0.f; }
#pragma unroll
        for (int j = 0; j < TJ; j++) {
            int c = wc * 128 + j * 16 + cn;
#pragma unroll
            for (int reg = 0; reg < 4; reg++) {
                float rv = acc[i][j][reg] + resid[(size_t)(trow + reg) * D_MODEL + c];
                acc[i][j][reg] = rv;
                s1p[i][reg] += rv;
                s2p[i][reg] = fmaf(rv, rv, s2p[i][reg]);
            }
        }
    }
#pragma unroll
    for (int m = 1; m < 16; m <<= 1) {
#pragma unroll
        for (int i = 0; i < TI; i++)
#pragma unroll
            for (int reg = 0; reg < 4; reg++) {
                s1p[i][reg] += __shfl_xor(s1p[i][reg], m);
                s2p[i][reg] += __shfl_xor(s2p[i][reg], m);
            }
    }
    if (cn == 0) {
#pragma unroll
        for (int i = 0; i < TI; i++)
#pragma unroll
            for (int reg = 0; reg < 4; reg++) {
                int rloc = wr * 32 + i * 16 + rq * 4 + reg;
                rs1[wc][rloc] = s1p[i][reg];
                rs2[wc][rloc] = s2p[i][reg];
            }
    }
    __syncthreads();
    float wv[TJ], bv[TJ];
#pragma unroll
    for (int j = 0; j < TJ; j++) {
        int c = wc * 128 + j * 16 + cn;
        wv[j] = w[c];
        bv[j] = b[c];
    }
#pragma unroll
    for (int i = 0; i < TI; i++) {
        int trow = t0 + wr * 32 + i * 16 + rq * 4;
#pragma unroll
        for (int reg = 0; reg < 4; reg++) {
            int rloc = wr * 32 + i * 16 + rq * 4 + reg;
            float S1 = rs1[0][rloc] + rs1[1][rloc];
            float S2 = rs2[0][rloc] + rs2[1][rloc];
            float mean, rstd;
            if constexpr (RMS) {
                mean = 0.f;
                rstd = rsqrtf(S2 * (1.f / D_MODEL) + 1e-5f);
            } else {
                mean = S1 * (1.f / D_MODEL);
                float var = S2 * (1.f / D_MODEL) - mean * mean;
                rstd = rsqrtf(var + 1e-5f);
            }
#pragma unroll
            for (int j = 0; j < TJ; j++) {
                int c = wc * 128 + j * 16 + cn;
                float rv = acc[i][j][reg];
                hb[(size_t)(trow + reg) * D_MODEL + c] =
                    f2b((rv - mean) * rstd * wv[j] + bv[j]);
                if constexpr (!RMS)
                    resid[(size_t)(trow + reg) * D_MODEL + c] = rv;
            }
        }
    }
}

// ------------- causal conv (k=4) + bias + SiLU; bf16 in, bf16 out -------------
__global__ void conv_silu_kernel(const unsigned short* __restrict__ xzb,
                                 const float* __restrict__ cW,
                                 const float* __restrict__ cb,
                                 unsigned short* __restrict__ xcb) {
    int idx = blockIdx.x * blockDim.x + threadIdx.x;  // 4-channel groups
    int d4 = (idx & 127) * 4;
    int t = idx >> 7;
    int l = t % SEQ;
    float4 acc = *(const float4*)(cb + d4);
    float4 wA = *(const float4*)(cW + (d4 + 0) * 4);
    float4 wB = *(const float4*)(cW + (d4 + 1) * 4);
    float4 wC = *(const float4*)(cW + (d4 + 2) * 4);
    float4 wD = *(const float4*)(cW + (d4 + 3) * 4);
#pragma unroll
    for (int k = 0; k < D_CONV; k++) {
        int ll = l - 3 + k;
        if (ll >= 0) {
            ushort4 u = *(const ushort4*)(xzb + (size_t)(t - 3 + k) * 1024 + d4);
            float wa = (k == 0) ? wA.x : (k == 1) ? wA.y : (k == 2) ? wA.z : wA.w;
            float wb = (k == 0) ? wB.x : (k == 1) ? wB.y : (k == 2) ? wB.z : wB.w;
            float wc = (k == 0) ? wC.x : (k == 1) ? wC.y : (k == 2) ? wC.z : wC.w;
            float wd = (k == 0) ? wD.x : (k == 1) ? wD.y : (k == 2) ? wD.z : wD.w;
            acc.x = fmaf(b2f(u.x), wa, acc.x);
            acc.y = fmaf(b2f(u.y), wb, acc.y);
            acc.z = fmaf(b2f(u.z), wc, acc.z);
            acc.w = fmaf(b2f(u.w), wd, acc.w);
        }
    }
    ushort4 ob;
    ob.x = f2b(acc.x * fast_sig(acc.x));
    ob.y = f2b(acc.y * fast_sig(acc.y));
    ob.z = f2b(acc.z * fast_sig(acc.z));
    ob.w = f2b(acc.w * fast_sig(acc.w));
    *(ushort4*)(xcb + (size_t)t * 512 + d4) = ob;
}

// ========== block-local 3-phase scan (r16 structure); grid (b, dg) for XCD L2 share ==========
__global__ __launch_bounds__(960) void scan_block(
    const unsigned short* __restrict__ xcb, const float* __restrict__ dbl,
    const unsigned short* __restrict__ xzb,
    const float* __restrict__ A_log, const float* __restrict__ Dskip,
    const float* __restrict__ dtW, const float* __restrict__ dtb,
    float* __restrict__ dts, unsigned short* __restrict__ yb) {
    __shared__ float lh[NSEG * D_STATE * 64];
    __shared__ float lsd[NSEG * 64];
    const int b = blockIdx.x, dg = blockIdx.y;   // same-b blocks land on same XCD
    const int tid = threadIdx.x;
    const int lane = tid & 63;
    const int seg = __builtin_amdgcn_readfirstlane(tid >> 6);  // wave-uniform
    const int d = (dg << 6) + lane;
    const float LOG2E = 1.44269504088896340736f;
    float ArowL2[D_STATE], dWr[DT_RANK];
#pragma unroll
    for (int s4 = 0; s4 < 4; s4++) {
        float4 v = *(const float4*)(A_log + (size_t)d * D_STATE + s4 * 4);
        ArowL2[s4 * 4 + 0] = -__expf(v.x) * LOG2E;
        ArowL2[s4 * 4 + 1] = -__expf(v.y) * LOG2E;
        ArowL2[s4 * 4 + 2] = -__expf(v.z) * LOG2E;
        ArowL2[s4 * 4 + 3] = -__expf(v.w) * LOG2E;
        float4 w = *(const float4*)(dtW + (size_t)d * DT_RANK + s4 * 4);
        dWr[s4 * 4 + 0] = w.x; dWr[s4 * 4 + 1] = w.y;
        dWr[s4 * 4 + 2] = w.z; dWr[s4 * 4 + 3] = w.w;
    }
    const float dtbv = dtb[d], dsk = Dskip[d];
    const size_t tb = (size_t)b * SEQ + (size_t)seg * SEGLEN;
    const float* __restrict__ dr = dbl + tb * 48;
    const unsigned short* __restrict__ xp = xcb + tb * 512 + d;
    const unsigned short* __restrict__ zp = xzb + tb * 1024 + 512 + d;
    float* __restrict__ dtp = dts + tb * 512 + d;
    unsigned short* __restrict__ yp = yb + tb * 512 + d;

    // ---------------- phase 1: local scan from h=0; record dtt ----------------
    {
        float h[D_STATE];
#pragma unroll
        for (int s = 0; s < D_STATE; s++) h[s] = 0.f;
        float sdt = 0.f;
        float dbA[32], dbB[32];
#pragma unroll
        for (int i = 0; i < 8; i++) ((float4*)dbA)[i] = ((const float4*)dr)[i];
        float xv = b2f(xp[0]);
        for (int l = 0; l < SEGLEN; l += 2) {
            const float4* nr1 = (const float4*)(dr + (size_t)(l + 1) * 48);
#pragma unroll
            for (int i = 0; i < 8; i++) ((float4*)dbB)[i] = nr1[i];
            float xv1 = b2f(xp[(size_t)(l + 1) * 512]);
            {
                float a0 = dtbv, a1 = 0.f, a2 = 0.f, a3 = 0.f;
#pragma unroll
                for (int r = 0; r < 4; r++) {
                    a0 = fmaf(dbA[r], dWr[r], a0);
                    a1 = fmaf(dbA[4 + r], dWr[4 + r], a1);
                    a2 = fmaf(dbA[8 + r], dWr[8 + r], a2);
                    a3 = fmaf(dbA[12 + r], dWr[12 + r], a3);
                }
                float acc = (a0 + a1) + (a2 + a3);
                float dtt = fmaxf(acc, 0.f) + __logf(1.f + __expf(-fabsf(acc)));
                dtp[(size_t)l * 512] = dtt;
                sdt += dtt;
                float dtx = dtt * xv;
#pragma unroll
                for (int s = 0; s < D_STATE; s++) {
                    float dA = exp2f(dtt * ArowL2[s]);
                    h[s] = fmaf(dA, h[s], dtx * dbA[16 + s]);
                }
            }
            const float4* nr2 = (const float4*)(dr + (size_t)(l + 2) * 48);
#pragma unroll
            for (int i = 0; i < 8; i++) ((float4*)dbA)[i] = nr2[i];
            float xv2 = b2f(xp[(size_t)(l + 2) * 512]);
            if (l + 1 < SEGLEN) {
                float a0 = dtbv, a1 = 0.f, a2 = 0.f, a3 = 0.f;
#pragma unroll
                for (int r = 0; r < 4; r++) {
                    a0 = fmaf(dbB[r], dWr[r], a0);
                    a1 = fmaf(dbB[4 + r], dWr[4 + r], a1);
                    a2 = fmaf(dbB[8 + r], dWr[8 + r], a2);
                    a3 = fmaf(dbB[12 + r], dWr[12 + r], a3);
                }
                float acc = (a0 + a1) + (a2 + a3);
                float dtt = fmaxf(acc, 0.f) + __logf(1.f + __expf(-fabsf(acc)));
                dtp[(size_t)(l + 1) * 512] = dtt;
                sdt += dtt;
                float dtx = dtt * xv1;
#pragma unroll
                for (int s = 0; s < D_STATE; s++) {
                    float dA = exp2f(dtt * ArowL2[s]);
                    h[s] = fmaf(dA, h[s], dtx * dbB[16 + s]);
                }
            }
            xv = xv2;
        }
#pragma unroll
        for (int s = 0; s < D_STATE; s++) lh[(seg * D_STATE + s) * 64 + lane] = h[s];
        lsd[seg * 64 + lane] = sdt;
    }
    __syncthreads();
    // ---------------- phase 2: in-LDS prefix combine ----------------
    for (int it = tid; it < D_STATE * 64; it += 960) {
        int ch = it & 63, s = it >> 6;
        float As2 = -__expf(A_log[(size_t)((dg << 6) + ch) * D_STATE + s]) * LOG2E;
        float H = 0.f;
        for (int sg = 0; sg < NSEG; sg++) {
            float hl = lh[(sg * D_STATE + s) * 64 + ch];
            float sd = lsd[sg * 64 + ch];
            lh[(sg * D_STATE + s) * 64 + ch] = H;
            H = fmaf(exp2f(As2 * sd), H, hl);
        }
    }
    __syncthreads();
    // ---------------- phase 3: re-scan from initial state (dtt cached; B,C rows only) ----------------
    {
        float h[D_STATE];
#pragma unroll
        for (int s = 0; s < D_STATE; s++) h[s] = lh[(seg * D_STATE + s) * 64 + lane];
        float dbA[32], dbB[32];
#pragma unroll
        for (int i = 0; i < 8; i++) ((float4*)dbA)[i] = ((const float4*)(dr + 16))[i];
        float xv = b2f(xp[0]), zv = b2f(zp[0]);
        float dt0 = dtp[0];
        for (int l = 0; l < SEGLEN; l += 2) {
            const float4* nr1 = (const float4*)(dr + (size_t)(l + 1) * 48 + 16);
#pragma unroll
            for (int i = 0; i < 8; i++) ((float4*)dbB)[i] = nr1[i];
            float xv1 = b2f(xp[(size_t)(l + 1) * 512]);
            float zv1 = b2f(zp[(size_t)(l + 1) * 1024]);
            float dt1 = dtp[(size_t)(l + 1) * 512];
            {
                float dtt = dt0;
                float dtx = dtt * xv;
                float y0 = 0.f, y1 = 0.f, y2 = 0.f, y3 = 0.f;
#pragma unroll
                for (int s = 0; s < 4; s++) {
                    float dA0 = exp2f(dtt * ArowL2[s]);
                    float dA1 = exp2f(dtt * ArowL2[4 + s]);
                    float dA2 = exp2f(dtt * ArowL2[8 + s]);
                    float dA3 = exp2f(dtt * ArowL2[12 + s]);
                    h[s] = fmaf(dA0, h[s], dtx * dbA[s]);
                    h[4 + s] = fmaf(dA1, h[4 + s], dtx * dbA[4 + s]);
                    h[8 + s] = fmaf(dA2, h[8 + s], dtx * dbA[8 + s]);
                    h[12 + s] = fmaf(dA3, h[12 + s], dtx * dbA[12 + s]);
                    y0 = fmaf(h[s], dbA[16 + s], y0);
                    y1 = fmaf(h[4 + s], dbA[20 + s], y1);
                    y2 = fmaf(h[8 + s], dbA[24 + s], y2);
                    y3 = fmaf(h[12 + s], dbA[28 + s], y3);
                }
                float y = (y0 + y1) + (y2 + y3);
                yp[(size_t)l * 512] = f2b((y + xv * dsk) * (zv * fast_sig(zv)));
            }
            const float4* nr2 = (const float4*)(dr + (size_t)(l + 2) * 48 + 16);
#pragma unroll
            for (int i = 0; i < 8; i++) ((float4*)dbA)[i] = nr2[i];
            float xv2 = b2f(xp[(size_t)(l + 2) * 512]);
            float zv2 = b2f(zp[(size_t)(l + 2) * 1024]);
            float dt2 = dtp[(size_t)(l + 2) * 512];
            if (l + 1 < SEGLEN) {
                float dtt = dt1;
                float dtx = dtt * xv1;
                float y0 = 0.f, y1 = 0.f, y2 = 0.f, y3 = 0.f;
#pragma unroll
                for (int s = 0; s < 4; s++) {
                    float dA0 = exp2f(dtt * ArowL2[s]);
                    float dA1 = exp2f(dtt * ArowL2[4 + s]);
                    float dA2 = exp2f(dtt * ArowL2[8 + s]);
                    float dA3 = exp2f(dtt * ArowL2[12 + s]);
                    h[s] = fmaf(dA0, h[s], dtx * dbB[s]);
                    h[4 + s] = fmaf(dA1, h[4 + s], dtx * dbB[4 + s]);
                    h[8 + s] = fmaf(dA2, h[8 + s], dtx * dbB[8 + s]);
                    h[12 + s] = fmaf(dA3, h[12 + s], dtx * dbB[12 + s]);
                    y0 = fmaf(h[s], dbB[16 + s], y0);
                    y1 = fmaf(h[4 + s], dbB[20 + s], y1);
                    y2 = fmaf(h[8 + s], dbB[24 + s], y2);
                    y3 = fmaf(h[12 + s], dbB[28 + s], y3);
                }
                float y = (y0 + y1) + (y2 + y3);
                yp[(size_t)(l + 1) * 512] = f2b((y + xv1 * dsk) * (zv1 * fast_sig(zv1)));
            }
            xv = xv2; zv = zv2; dt0 = dt2;
        }
    }
}

extern "C" void kernel_launch(void* const* d_in, const int* in_sizes, int n_in,
                              void* d_out, int out_size, void* d_ws, size_t ws_size,
                              hipStream_t stream) {
    const float* coords   = (const float*)d_in[0];
    const float* emb_W    = (const float*)d_in[1];
    const float* emb_b    = (const float*)d_in[2];
    const float* ln_w     = (const float*)d_in[3];
    const float* ln_b     = (const float*)d_in[4];
    const float* in_W     = (const float*)d_in[5];
    const float* conv_W   = (const float*)d_in[6];
    const float* conv_b   = (const float*)d_in[7];
    const float* xproj_W  = (const float*)d_in[8];
    const float* dtproj_W = (const float*)d_in[9];
    const float* dtproj_b = (const float*)d_in[10];
    const float* A_log    = (const float*)d_in[11];
    const float* D_skip   = (const float*)d_in[12];
    const float* out_W    = (const float*)d_in[13];
    const float* normf_w  = (const float*)d_in[14];
    const float* normf_b  = (const float*)d_in[15];
    const float* head_W   = (const float*)d_in[16];
    float* out = (float*)d_out;

    const int T = NTOK;  // 9600
    float* resid = (float*)d_ws;
    float* dbl   = resid + (size_t)T * D_MODEL;
    float* dts   = dbl + (size_t)T * 48;
    unsigned short* hb     = (unsigned short*)(dts + (size_t)T * D_INNER);
    unsigned short* xzb    = hb + (size_t)T * D_MODEL;
    unsigned short* xcb    = xzb + (size_t)T * 2 * D_INNER;
    unsigned short* yb     = xcb + (size_t)T * D_INNER;
    unsigned short* wb_in  = yb + (size_t)T * D_INNER;
    unsigned short* wb_xp  = wb_in + (size_t)N_LAYERS * 2 * D_INNER * D_MODEL;
    unsigned short* wb_out = wb_xp + (size_t)N_LAYERS * 48 * D_INNER;
    unsigned short* wb_hd  = wb_out + (size_t)N_LAYERS * D_MODEL * D_INNER;

    cvt4_kernel<<<256, 256, 0, stream>>>(
        in_W, wb_in, N_LAYERS * 2 * D_INNER * D_MODEL,
        xproj_W, wb_xp, N_LAYERS * 48 * D_INNER,
        out_W, wb_out, N_LAYERS * D_MODEL * D_INNER,
        head_W, wb_hd, CITY * D_MODEL);

    embed_ln_kernel<<<T, D_MODEL, 0, stream>>>(coords, emb_W, emb_b, ln_w, ln_b, resid, hb);

    for (int i = 0; i < N_LAYERS; i++) {
        // in_proj: (9600,256) x (1024,256)^T -> (9600,1024) bf16
        gemm_mfma<128, 128, false, true><<<dim3(T / 128, 8), 256, 0, stream>>>(
            hb, wb_in + (size_t)i * 2 * D_INNER * D_MODEL, xzb, 2 * D_INNER, D_MODEL);
        conv_silu_kernel<<<T * 128 / 256, 256, 0, stream>>>(
            xzb, conv_W + i * D_INNER * D_CONV, conv_b + i * D_INNER, xcb);
        // xproj: (9600,512) x (48,512)^T -> (9600,48) f32
        gemm_mfma<64, 64, true, false><<<dim3(T / 64, 1), 256, 0, stream>>>(
            xcb, wb_xp + (size_t)i * 48 * D_INNER, dbl, 48, D_INNER);
        // scan -> yb bf16 (dtt stashed in dts); grid (b, dg) for XCD dbl sharing
        scan_block<<<dim3(BATCH, 8), 960, 0, stream>>>(
            xcb, dbl, xzb, A_log + (size_t)i * D_INNER * D_STATE, D_skip + i * D_INNER,
            dtproj_W + (size_t)i * D_INNER * DT_RANK, dtproj_b + i * D_INNER, dts, yb);
        // out_proj + residual + LN (layers 0-2) / RMS (layer 3) fused
        if (i < N_LAYERS - 1)
            gemm_out_ln<false><<<T / 64, 256, 0, stream>>>(
                yb, wb_out + (size_t)i * D_MODEL * D_INNER, resid,
                ln_w + (i + 1) * D_MODEL, ln_b + (i + 1) * D_MODEL, hb);
        else
            gemm_out_ln<true><<<T / 64, 256, 0, stream>>>(
                yb, wb_out + (size_t)i * D_MODEL * D_INNER, resid,
                normf_w, normf_b, hb);
    }

    // head: (9600,256) x (300,256)^T -> (9600,300) f32
    gemm_mfma<64, 64, true, false><<<dim3(T / 64, 5), 256, 0, stream>>>(
        hb, wb_hd, out, CITY, D_MODEL);
}